// Round 13
// baseline (348.733 us; speedup 1.0000x reference)
//
#include <hip/hip_runtime.h>

constexpr int S_LEN = 2048;
constexpr int D_K   = 64;
constexpr int N_BH  = 32;   // B*H
constexpr int KB    = 64;   // k per chunk

typedef __attribute__((ext_vector_type(8))) short short8;
typedef __attribute__((ext_vector_type(4))) float f32x4;
typedef unsigned short ushort_t;

__device__ __forceinline__ unsigned short f2bf(float f) {
    unsigned int u = __builtin_bit_cast(unsigned int, f);
    u += 0x7fffu + ((u >> 16) & 1u);          // round-to-nearest-even
    return (unsigned short)(u >> 16);
}
__device__ __forceinline__ float bf2f(unsigned short h) {
    unsigned int u = ((unsigned int)h) << 16;
    return __builtin_bit_cast(float, u);
}

// ============================ prep kernels ============================
__global__ __launch_bounds__(256)
void prep_k(const float* __restrict__ K, ushort_t* __restrict__ Kws) {
    const int idx = blockIdx.x * 256 + threadIdx.x;
    const float4* src = (const float4*)K + (size_t)idx * 2;
    float4 a = src[0], b = src[1];
    float x[8] = {a.x, a.y, a.z, a.w, b.x, b.y, b.z, b.w};
    short8 o;
    #pragma unroll
    for (int j = 0; j < 8; ++j) o[j] = (short)f2bf(x[j] * 0.125f);
    *(short8*)(Kws + (size_t)idx * 8) = o;
}

__global__ __launch_bounds__(256)
void prep_v(const float* __restrict__ V, ushort_t* __restrict__ Vws) {
    const int gid = blockIdx.x * 256 + threadIdx.x;
    const int u   = gid & 511;
    const int bc  = gid >> 9;
    const int c   = bc & 31;
    const int bh  = bc >> 5;
    const int kg  = u >> 6;
    const int d   = u & 63;
    const float* vp = V + ((size_t)bh * S_LEN + c * KB + kg * 8) * D_K + d;
    short8 o;
    #pragma unroll
    for (int i = 0; i < 8; ++i) o[i] = (short)f2bf(vp[(size_t)i * D_K]);
    *(short8*)(Vws + ((size_t)(bh * 32 + c) * D_K + d) * KB + kg * 8) = o;
}

// ============================ main kernel =============================
// 512 blocks x 256 threads (4 waves). Block handles the PAIR of same-bh tiles
// A = 2p+1 (nchA = 2p+2) and B = 2p (nchB = 2p+1), which consume the SAME
// K/V chunks. Schedule:
//   phase 1: pass1(A)              (compute-only prologue)
//   middle : pass2(A) + pass1(B)   per staged chunk -> writes and compute
//            mixed every iteration; pass1(B) staging cost is ZERO.
//   phase 3: pass2(B)
// 3*nch chunk-iterations per pair vs 4*nch in the round-6 one-tile scheme
// (-25%), and the middle third keeps the HBM write pipe fed during compute.
// Shortest pairs dispatch first (R6's winning order). Numerics identical to
// R6: hi-only sums, hi+lo written values.
__global__ __launch_bounds__(256, 4)
void sdpa_main(const float* __restrict__ Q, const ushort_t* __restrict__ Kws,
               const ushort_t* __restrict__ Vws, float* __restrict__ out)
{
    __shared__ __align__(16) ushort_t Kbuf[2][4096];   // 16 KB
    __shared__ __align__(16) ushort_t Vbuf[2][4096];   // 16 KB
    __shared__ __align__(16) ushort_t Plds[4][1024];   //  8 KB (per-wave 16x64)

    const int tid = threadIdx.x;
    const int w   = tid >> 6;      // wave 0..3, owns 16 q rows of current tile
    const int l   = tid & 63;
    const int lr  = l & 15;
    const int lh  = l >> 4;

    const int b   = blockIdx.x;    // 0..511, shortest pairs first
    const int p   = b >> 5;        // 0..15
    const int bh  = b & 31;
    const int nchB = 2 * p + 1;
    const int nchA = 2 * p + 2;
    const int q0B  = (2 * p) * 64;
    const int q0A  = (2 * p + 1) * 64;
    const int qgA  = q0A + w * 16 + lh * 4;   // + rr = lane's q rows in tile A
    const int qgB  = q0B + w * 16 + lh * 4;

    float* ctx_out  = out;                                   // [BH][S][D]
    float* attn_out = out + (size_t)N_BH * S_LEN * D_K;      // [BH][S][S]

    const short8* Kt  = (const short8*)(Kws + (size_t)bh * S_LEN * D_K);   // chunk c at c*512
    const short8* Vt8 = (const short8*)(Vws + (size_t)bh * 32 * 4096);

    // staging: thread writes units tid and tid+256 of each 512-unit chunk
    const int wrow0  = tid >> 3;                  // 0..31
    const int wcol   = (tid & 7) << 4;
    const int wphys0 = wrow0 * 128 + (wcol ^ ((wrow0 & 7) << 4));
    const int wphys1 = wphys0 + 32 * 128;         // rows 32..63, same (row&7)
    const int rsw    = (lr & 7) << 4;             // K/V frag-read swizzle (bytes)

    // ---- Q fragments: A hi/lo, B hi only (B lo rebuilt before phase 3) ----
    short8 qhiA[2], qloA[2], qhiB[2];
    {
        const float* qrowA = Q + ((size_t)bh * S_LEN + q0A + w * 16 + lr) * D_K;
        const float* qrowB = Q + ((size_t)bh * S_LEN + q0B + w * 16 + lr) * D_K;
        #pragma unroll
        for (int ds = 0; ds < 2; ++ds) {
            const float4* pa = (const float4*)(qrowA + ds * 32 + lh * 8);
            float4 a0 = pa[0], a1 = pa[1];
            float xa[8] = {a0.x, a0.y, a0.z, a0.w, a1.x, a1.y, a1.z, a1.w};
            short8 hi, lo;
            #pragma unroll
            for (int j = 0; j < 8; ++j) {
                unsigned short h = f2bf(xa[j]);
                hi[j] = (short)h;
                lo[j] = (short)f2bf(xa[j] - bf2f(h));
            }
            qhiA[ds] = hi; qloA[ds] = lo;

            const float4* pb = (const float4*)(qrowB + ds * 32 + lh * 8);
            float4 b0 = pb[0], b1 = pb[1];
            float xb[8] = {b0.x, b0.y, b0.z, b0.w, b1.x, b1.y, b1.z, b1.w};
            short8 hb;
            #pragma unroll
            for (int j = 0; j < 8; ++j) hb[j] = (short)f2bf(xb[j]);
            qhiB[ds] = hb;
        }
    }

    // ================= PHASE 1: pass1(A) — K-only, hi-A =================
    float invA[4];
    {
        float sum[4] = {0.f, 0.f, 0.f, 0.f};

        auto p1A = [&](const char* Kb, int c) {
            #pragma unroll
            for (int nt = 0; nt < 4; ++nt) {
                f32x4 acc = {0.f, 0.f, 0.f, 0.f};
                #pragma unroll
                for (int ks = 0; ks < 2; ++ks) {
                    short8 bk = *(const short8*)(Kb + (nt * 16 + lr) * 128 + ((ks * 64 + lh * 16) ^ rsw));
                    acc = __builtin_amdgcn_mfma_f32_16x16x32_bf16(qhiA[ks], bk, acc, 0, 0, 0);
                }
                const int kg = c * KB + nt * 16 + lr;
                #pragma unroll
                for (int rr = 0; rr < 4; ++rr)
                    if (kg <= qgA + rr) sum[rr] += __expf(fminf(acc[rr], 60.f));
            }
        };

        short8 kE0 = Kt[tid], kE1 = Kt[tid + 256];             // chunk 0
        *(short8*)((char*)&Kbuf[0][0] + wphys0) = kE0;
        *(short8*)((char*)&Kbuf[0][0] + wphys1) = kE1;
        short8 kO0 = Kt[512 + tid], kO1 = Kt[512 + tid + 256]; // chunk 1 (nchA >= 2)
        __syncthreads();
        for (int c = 0; c < nchA; c += 2) {
            if (c + 2 < nchA) { kE0 = Kt[(c + 2) * 512 + tid]; kE1 = Kt[(c + 2) * 512 + tid + 256]; }
            p1A((const char*)&Kbuf[0][0], c);
            if (c + 1 < nchA) {
                *(short8*)((char*)&Kbuf[1][0] + wphys0) = kO0;
                *(short8*)((char*)&Kbuf[1][0] + wphys1) = kO1;
            }
            __syncthreads();
            if (c + 1 < nchA) {
                if (c + 3 < nchA) { kO0 = Kt[(c + 3) * 512 + tid]; kO1 = Kt[(c + 3) * 512 + tid + 256]; }
                p1A((const char*)&Kbuf[1][0], c + 1);
                if (c + 2 < nchA) {
                    *(short8*)((char*)&Kbuf[0][0] + wphys0) = kE0;
                    *(short8*)((char*)&Kbuf[0][0] + wphys1) = kE1;
                }
                __syncthreads();
            }
        }
        #pragma unroll
        for (int rr = 0; rr < 4; ++rr) {
            float s = sum[rr];
            s += __shfl_xor(s, 1);
            s += __shfl_xor(s, 2);
            s += __shfl_xor(s, 4);
            s += __shfl_xor(s, 8);
            invA[rr] = 1.f / s;
        }
    }

    // ============ MIDDLE: pass2(A) + pass1(B) per staged chunk ============
    f32x4 ctx[4];
    #pragma unroll
    for (int nt = 0; nt < 4; ++nt) ctx[nt] = (f32x4){0.f, 0.f, 0.f, 0.f};
    float sumB[4] = {0.f, 0.f, 0.f, 0.f};

    {
        auto mid = [&](const char* Kb, const char* Vb, int c) {
            // pass2(A): QK hi/lo, write attn A, stage P, PV
            #pragma unroll
            for (int nt = 0; nt < 4; ++nt) {
                f32x4 acc = {0.f, 0.f, 0.f, 0.f};
                #pragma unroll
                for (int ks = 0; ks < 2; ++ks) {
                    short8 bk = *(const short8*)(Kb + (nt * 16 + lr) * 128 + ((ks * 64 + lh * 16) ^ rsw));
                    acc = __builtin_amdgcn_mfma_f32_16x16x32_bf16(qhiA[ks], bk, acc, 0, 0, 0);
                    acc = __builtin_amdgcn_mfma_f32_16x16x32_bf16(qloA[ks], bk, acc, 0, 0, 0);
                }
                const int kg = c * KB + nt * 16 + lr;
                #pragma unroll
                for (int rr = 0; rr < 4; ++rr) {
                    const int pwr = lh * 4 + rr;
                    const int qg  = qgA + rr;
                    float pv = (kg <= qg) ? __expf(fminf(acc[rr], 60.f)) * invA[rr] : 0.f;
                    attn_out[((size_t)bh * S_LEN + qg) * S_LEN + kg] = pv;
                    Plds[w][pwr * 64 + ((nt * 16 + lr) ^ ((pwr & 7) << 3))] = f2bf(pv);
                }
            }
            #pragma unroll
            for (int ks = 0; ks < 2; ++ks) {
                short8 pa = *(const short8*)&Plds[w][lr * 64 + ((ks * 32 + lh * 8) ^ ((lr & 7) << 3))];
                #pragma unroll
                for (int nt = 0; nt < 4; ++nt) {
                    short8 vb = *(const short8*)(Vb + (nt * 16 + lr) * 128 + ((ks * 64 + lh * 16) ^ rsw));
                    ctx[nt] = __builtin_amdgcn_mfma_f32_16x16x32_bf16(pa, vb, ctx[nt], 0, 0, 0);
                }
            }
            // pass1(B): hi-only QK on the SAME staged chunk (zero staging cost)
            if (c < nchB) {
                #pragma unroll
                for (int nt = 0; nt < 4; ++nt) {
                    f32x4 acc = {0.f, 0.f, 0.f, 0.f};
                    #pragma unroll
                    for (int ks = 0; ks < 2; ++ks) {
                        short8 bk = *(const short8*)(Kb + (nt * 16 + lr) * 128 + ((ks * 64 + lh * 16) ^ rsw));
                        acc = __builtin_amdgcn_mfma_f32_16x16x32_bf16(qhiB[ks], bk, acc, 0, 0, 0);
                    }
                    const int kg = c * KB + nt * 16 + lr;
                    #pragma unroll
                    for (int rr = 0; rr < 4; ++rr)
                        if (kg <= qgB + rr) sumB[rr] += __expf(fminf(acc[rr], 60.f));
                }
            }
        };

        short8 kE0 = Kt[tid],        kE1 = Kt[tid + 256];
        short8 vE0 = Vt8[tid],       vE1 = Vt8[tid + 256];
        *(short8*)((char*)&Kbuf[0][0] + wphys0) = kE0;
        *(short8*)((char*)&Kbuf[0][0] + wphys1) = kE1;
        *(short8*)((char*)&Vbuf[0][0] + wphys0) = vE0;
        *(short8*)((char*)&Vbuf[0][0] + wphys1) = vE1;
        short8 kO0 = Kt[512 + tid],  kO1 = Kt[512 + tid + 256];
        short8 vO0 = Vt8[512 + tid], vO1 = Vt8[512 + tid + 256];
        __syncthreads();
        for (int c = 0; c < nchA; c += 2) {
            if (c + 2 < nchA) {
                kE0 = Kt[(c + 2) * 512 + tid];  kE1 = Kt[(c + 2) * 512 + tid + 256];
                vE0 = Vt8[(c + 2) * 512 + tid]; vE1 = Vt8[(c + 2) * 512 + tid + 256];
            }
            mid((const char*)&Kbuf[0][0], (const char*)&Vbuf[0][0], c);
            if (c + 1 < nchA) {
                *(short8*)((char*)&Kbuf[1][0] + wphys0) = kO0;
                *(short8*)((char*)&Kbuf[1][0] + wphys1) = kO1;
                *(short8*)((char*)&Vbuf[1][0] + wphys0) = vO0;
                *(short8*)((char*)&Vbuf[1][0] + wphys1) = vO1;
            }
            __syncthreads();
            if (c + 1 < nchA) {
                if (c + 3 < nchA) {
                    kO0 = Kt[(c + 3) * 512 + tid];  kO1 = Kt[(c + 3) * 512 + tid + 256];
                    vO0 = Vt8[(c + 3) * 512 + tid]; vO1 = Vt8[(c + 3) * 512 + tid + 256];
                }
                mid((const char*)&Kbuf[1][0], (const char*)&Vbuf[1][0], c + 1);
                if (c + 2 < nchA) {
                    *(short8*)((char*)&Kbuf[0][0] + wphys0) = kE0;
                    *(short8*)((char*)&Kbuf[0][0] + wphys1) = kE1;
                    *(short8*)((char*)&Vbuf[0][0] + wphys0) = vE0;
                    *(short8*)((char*)&Vbuf[0][0] + wphys1) = vE1;
                }
                __syncthreads();
            }
        }
    }

    // store ctx(A)
    #pragma unroll
    for (int nt = 0; nt < 4; ++nt)
        #pragma unroll
        for (int rr = 0; rr < 4; ++rr)
            ctx_out[((size_t)bh * S_LEN + qgA + rr) * D_K + nt * 16 + lr] = ctx[nt][rr];

    // sums(B) -> invB; rebuild qloB from Q
    float invB[4];
    #pragma unroll
    for (int rr = 0; rr < 4; ++rr) {
        float s = sumB[rr];
        s += __shfl_xor(s, 1);
        s += __shfl_xor(s, 2);
        s += __shfl_xor(s, 4);
        s += __shfl_xor(s, 8);
        invB[rr] = 1.f / s;
    }
    short8 qloB[2];
    {
        const float* qrowB = Q + ((size_t)bh * S_LEN + q0B + w * 16 + lr) * D_K;
        #pragma unroll
        for (int ds = 0; ds < 2; ++ds) {
            const float4* pb = (const float4*)(qrowB + ds * 32 + lh * 8);
            float4 b0 = pb[0], b1 = pb[1];
            float xb[8] = {b0.x, b0.y, b0.z, b0.w, b1.x, b1.y, b1.z, b1.w};
            short8 lo;
            #pragma unroll
            for (int j = 0; j < 8; ++j) {
                unsigned short h = f2bf(xb[j]);
                lo[j] = (short)f2bf(xb[j] - bf2f(h));
            }
            qloB[ds] = lo;
        }
    }

    // ================= PHASE 3: pass2(B) =================
    #pragma unroll
    for (int nt = 0; nt < 4; ++nt) ctx[nt] = (f32x4){0.f, 0.f, 0.f, 0.f};

    {
        auto p2B = [&](const char* Kb, const char* Vb, int c) {
            #pragma unroll
            for (int nt = 0; nt < 4; ++nt) {
                f32x4 acc = {0.f, 0.f, 0.f, 0.f};
                #pragma unroll
                for (int ks = 0; ks < 2; ++ks) {
                    short8 bk = *(const short8*)(Kb + (nt * 16 + lr) * 128 + ((ks * 64 + lh * 16) ^ rsw));
                    acc = __builtin_amdgcn_mfma_f32_16x16x32_bf16(qhiB[ks], bk, acc, 0, 0, 0);
                    acc = __builtin_amdgcn_mfma_f32_16x16x32_bf16(qloB[ks], bk, acc, 0, 0, 0);
                }
                const int kg = c * KB + nt * 16 + lr;
                #pragma unroll
                for (int rr = 0; rr < 4; ++rr) {
                    const int pwr = lh * 4 + rr;
                    const int qg  = qgB + rr;
                    float pv = (kg <= qg) ? __expf(fminf(acc[rr], 60.f)) * invB[rr] : 0.f;
                    attn_out[((size_t)bh * S_LEN + qg) * S_LEN + kg] = pv;
                    Plds[w][pwr * 64 + ((nt * 16 + lr) ^ ((pwr & 7) << 3))] = f2bf(pv);
                }
            }
            #pragma unroll
            for (int ks = 0; ks < 2; ++ks) {
                short8 pa = *(const short8*)&Plds[w][lr * 64 + ((ks * 32 + lh * 8) ^ ((lr & 7) << 3))];
                #pragma unroll
                for (int nt = 0; nt < 4; ++nt) {
                    short8 vb = *(const short8*)(Vb + (nt * 16 + lr) * 128 + ((ks * 64 + lh * 16) ^ rsw));
                    ctx[nt] = __builtin_amdgcn_mfma_f32_16x16x32_bf16(pa, vb, ctx[nt], 0, 0, 0);
                }
            }
        };

        short8 kE0 = Kt[tid],        kE1 = Kt[tid + 256];
        short8 vE0 = Vt8[tid],       vE1 = Vt8[tid + 256];
        *(short8*)((char*)&Kbuf[0][0] + wphys0) = kE0;
        *(short8*)((char*)&Kbuf[0][0] + wphys1) = kE1;
        *(short8*)((char*)&Vbuf[0][0] + wphys0) = vE0;
        *(short8*)((char*)&Vbuf[0][0] + wphys1) = vE1;
        short8 kO0, kO1, vO0, vO1;
        if (nchB > 1) {
            kO0 = Kt[512 + tid];  kO1 = Kt[512 + tid + 256];
            vO0 = Vt8[512 + tid]; vO1 = Vt8[512 + tid + 256];
        }
        __syncthreads();
        for (int c = 0; c < nchB; c += 2) {
            if (c + 2 < nchB) {
                kE0 = Kt[(c + 2) * 512 + tid];  kE1 = Kt[(c + 2) * 512 + tid + 256];
                vE0 = Vt8[(c + 2) * 512 + tid]; vE1 = Vt8[(c + 2) * 512 + tid + 256];
            }
            p2B((const char*)&Kbuf[0][0], (const char*)&Vbuf[0][0], c);
            if (c + 1 < nchB) {
                *(short8*)((char*)&Kbuf[1][0] + wphys0) = kO0;
                *(short8*)((char*)&Kbuf[1][0] + wphys1) = kO1;
                *(short8*)((char*)&Vbuf[1][0] + wphys0) = vO0;
                *(short8*)((char*)&Vbuf[1][0] + wphys1) = vO1;
            }
            __syncthreads();
            if (c + 1 < nchB) {
                if (c + 3 < nchB) {
                    kO0 = Kt[(c + 3) * 512 + tid];  kO1 = Kt[(c + 3) * 512 + tid + 256];
                    vO0 = Vt8[(c + 3) * 512 + tid]; vO1 = Vt8[(c + 3) * 512 + tid + 256];
                }
                p2B((const char*)&Kbuf[1][0], (const char*)&Vbuf[1][0], c + 1);
                if (c + 2 < nchB) {
                    *(short8*)((char*)&Kbuf[0][0] + wphys0) = kE0;
                    *(short8*)((char*)&Kbuf[0][0] + wphys1) = kE1;
                    *(short8*)((char*)&Vbuf[0][0] + wphys0) = vE0;
                    *(short8*)((char*)&Vbuf[0][0] + wphys1) = vE1;
                }
                __syncthreads();
            }
        }
    }

    // store ctx(B)
    #pragma unroll
    for (int nt = 0; nt < 4; ++nt)
        #pragma unroll
        for (int rr = 0; rr < 4; ++rr)
            ctx_out[((size_t)bh * S_LEN + qgB + rr) * D_K + nt * 16 + lr] = ctx[nt][rr];

    // zero-fill fully-masked tail columns for both tiles (64 rows, 4 thr/row)
    {
        const float4 z = {0.f, 0.f, 0.f, 0.f};
        const int k0A = nchA * KB;
        if (k0A < S_LEN) {
            float* rowp = attn_out + ((size_t)bh * S_LEN + q0A + (tid >> 2)) * S_LEN;
            for (int k = k0A + (tid & 3) * 4; k < S_LEN; k += 16)
                *(float4*)(rowp + k) = z;
        }
        const int k0B = nchB * KB;
        if (k0B < S_LEN) {
            float* rowp = attn_out + ((size_t)bh * S_LEN + q0B + (tid >> 2)) * S_LEN;
            for (int k = k0B + (tid & 3) * 4; k < S_LEN; k += 16)
                *(float4*)(rowp + k) = z;
        }
    }
}

// ===================== fallback (round-1 kernel, no ws) =====================
constexpr int LDP = 72;

__global__ __launch_bounds__(256)
void sdpa_fused_v1(const float* __restrict__ Q, const float* __restrict__ K,
                   const float* __restrict__ V, float* __restrict__ out)
{
    __shared__ __align__(16) unsigned short Klds[KB * LDP];
    __shared__ __align__(16) unsigned short Vtlds[D_K * LDP];
    __shared__ __align__(16) unsigned short Pl[4][16 * LDP];

    const int tid = threadIdx.x;
    const int w   = tid >> 6;
    const int l   = tid & 63;
    const int lr  = l & 15;
    const int lh  = l >> 4;

    const int bh   = blockIdx.y;
    const int qblk = (int)gridDim.x - 1 - (int)blockIdx.x;
    const int q0   = qblk * 64;
    const int qw   = q0 + w * 16;
    const int nchunks = qblk + 1;

    const size_t in_base = (size_t)bh * S_LEN * D_K;
    float* ctx_out  = out;
    float* attn_out = out + (size_t)N_BH * S_LEN * D_K;

    short8 qhi[2], qlo[2];
    {
        const float* qrow = Q + in_base + (size_t)(qw + lr) * D_K;
        #pragma unroll
        for (int ds = 0; ds < 2; ++ds) {
            const float4* p4 = (const float4*)(qrow + ds * 32 + lh * 8);
            float4 a = p4[0], b = p4[1];
            float x[8] = {a.x, a.y, a.z, a.w, b.x, b.y, b.z, b.w};
            short8 hi, lo;
            #pragma unroll
            for (int j = 0; j < 8; ++j) {
                unsigned short h = f2bf(x[j]);
                hi[j] = (short)h;
                lo[j] = (short)f2bf(x[j] - bf2f(h));
            }
            qhi[ds] = hi; qlo[ds] = lo;
        }
    }

    const int srow = tid >> 2;
    const int scol = (tid & 3) * 16;
    const float* kstage = K + in_base + (size_t)srow * D_K + scol;
    const float* vstage = V + in_base + (size_t)srow * D_K + scol;

    float inv_[4];
    {
        float sum[4] = {0.f, 0.f, 0.f, 0.f};
        for (int c = 0; c < nchunks; ++c) {
            {
                const float4* kp = (const float4*)(kstage + (size_t)c * KB * D_K);
                float4 a0 = kp[0], a1 = kp[1], a2 = kp[2], a3 = kp[3];
                float x[16] = {a0.x,a0.y,a0.z,a0.w, a1.x,a1.y,a1.z,a1.w,
                               a2.x,a2.y,a2.z,a2.w, a3.x,a3.y,a3.z,a3.w};
                short8 w0, w1;
                #pragma unroll
                for (int j = 0; j < 8; ++j) {
                    w0[j] = (short)f2bf(x[j]     * 0.125f);
                    w1[j] = (short)f2bf(x[j + 8] * 0.125f);
                }
                *(short8*)&Klds[srow * LDP + scol]     = w0;
                *(short8*)&Klds[srow * LDP + scol + 8] = w1;
            }
            __syncthreads();
            #pragma unroll
            for (int nt = 0; nt < 4; ++nt) {
                f32x4 acc = {0.f, 0.f, 0.f, 0.f};
                #pragma unroll
                for (int ks = 0; ks < 2; ++ks) {
                    short8 bk = *(const short8*)&Klds[(nt*16 + lr) * LDP + ks*32 + lh*8];
                    acc = __builtin_amdgcn_mfma_f32_16x16x32_bf16(qhi[ks], bk, acc, 0, 0, 0);
                    acc = __builtin_amdgcn_mfma_f32_16x16x32_bf16(qlo[ks], bk, acc, 0, 0, 0);
                }
                const int kg = c * KB + nt * 16 + lr;
                #pragma unroll
                for (int rr = 0; rr < 4; ++rr) {
                    if (kg <= qw + lh * 4 + rr)
                        sum[rr] += __expf(fminf(acc[rr], 60.f));
                }
            }
            __syncthreads();
        }
        #pragma unroll
        for (int rr = 0; rr < 4; ++rr) {
            float t = sum[rr];
            t += __shfl_xor(t, 1);
            t += __shfl_xor(t, 2);
            t += __shfl_xor(t, 4);
            t += __shfl_xor(t, 8);
            inv_[rr] = 1.f / t;
        }
    }

    f32x4 ctx[4];
    #pragma unroll
    for (int nt = 0; nt < 4; ++nt) ctx[nt] = (f32x4){0.f, 0.f, 0.f, 0.f};

    for (int c = 0; c < nchunks; ++c) {
        {
            const float4* kp = (const float4*)(kstage + (size_t)c * KB * D_K);
            float4 a0 = kp[0], a1 = kp[1], a2 = kp[2], a3 = kp[3];
            float x[16] = {a0.x,a0.y,a0.z,a0.w, a1.x,a1.y,a1.z,a1.w,
                           a2.x,a2.y,a2.z,a2.w, a3.x,a3.y,a3.z,a3.w};
            short8 w0, w1;
            #pragma unroll
            for (int j = 0; j < 8; ++j) {
                w0[j] = (short)f2bf(x[j]     * 0.125f);
                w1[j] = (short)f2bf(x[j + 8] * 0.125f);
            }
            *(short8*)&Klds[srow * LDP + scol]     = w0;
            *(short8*)&Klds[srow * LDP + scol + 8] = w1;

            const float4* vp = (const float4*)(vstage + (size_t)c * KB * D_K);
            float4 b0 = vp[0], b1 = vp[1], b2 = vp[2], b3 = vp[3];
            float y[16] = {b0.x,b0.y,b0.z,b0.w, b1.x,b1.y,b1.z,b1.w,
                           b2.x,b2.y,b2.z,b2.w, b3.x,b3.y,b3.z,b3.w};
            #pragma unroll
            for (int j = 0; j < 16; ++j)
                Vtlds[(scol + j) * LDP + srow] = f2bf(y[j]);
        }
        __syncthreads();

        #pragma unroll
        for (int nt = 0; nt < 4; ++nt) {
            f32x4 acc = {0.f, 0.f, 0.f, 0.f};
            #pragma unroll
            for (int ks = 0; ks < 2; ++ks) {
                short8 bk = *(const short8*)&Klds[(nt*16 + lr) * LDP + ks*32 + lh*8];
                acc = __builtin_amdgcn_mfma_f32_16x16x32_bf16(qhi[ks], bk, acc, 0, 0, 0);
                acc = __builtin_amdgcn_mfma_f32_16x16x32_bf16(qlo[ks], bk, acc, 0, 0, 0);
            }
            const int kg = c * KB + nt * 16 + lr;
            #pragma unroll
            for (int rr = 0; rr < 4; ++rr) {
                const int qg = qw + lh * 4 + rr;
                float p = (kg <= qg) ? __expf(fminf(acc[rr], 60.f)) * inv_[rr] : 0.f;
                attn_out[((size_t)bh * S_LEN + qg) * S_LEN + kg] = p;
                Pl[w][(lh * 4 + rr) * LDP + nt * 16 + lr] = f2bf(p);
            }
        }
        __syncthreads();

        #pragma unroll
        for (int ks = 0; ks < 2; ++ks) {
            short8 pa = *(const short8*)&Pl[w][lr * LDP + ks*32 + lh*8];
            #pragma unroll
            for (int nt = 0; nt < 4; ++nt) {
                short8 vb = *(const short8*)&Vtlds[(nt*16 + lr) * LDP + ks*32 + lh*8];
                ctx[nt] = __builtin_amdgcn_mfma_f32_16x16x32_bf16(pa, vb, ctx[nt], 0, 0, 0);
            }
        }
        __syncthreads();
    }

    #pragma unroll
    for (int nt = 0; nt < 4; ++nt)
        #pragma unroll
        for (int rr = 0; rr < 4; ++rr)
            ctx_out[((size_t)bh * S_LEN + qw + lh * 4 + rr) * D_K + nt * 16 + lr] = ctx[nt][rr];

    const int k0 = nchunks * KB;
    if (k0 < S_LEN) {
        const float4 z = {0.f, 0.f, 0.f, 0.f};
        for (int rr = 0; rr < 64; ++rr) {
            float* rowp = attn_out + ((size_t)bh * S_LEN + q0 + rr) * S_LEN;
            for (int k = k0 + tid * 4; k < S_LEN; k += 256 * 4)
                *(float4*)(rowp + k) = z;
        }
    }
}

extern "C" void kernel_launch(void* const* d_in, const int* in_sizes, int n_in,
                              void* d_out, int out_size, void* d_ws, size_t ws_size,
                              hipStream_t stream)
{
    const float* Q = (const float*)d_in[0];
    const float* K = (const float*)d_in[1];
    const float* V = (const float*)d_in[2];
    float* out = (float*)d_out;

    const size_t ws_needed = (size_t)2 * N_BH * S_LEN * D_K * sizeof(ushort_t);  // 16.8 MB
    if (ws_size >= ws_needed) {
        ushort_t* Kws = (ushort_t*)d_ws;
        ushort_t* Vws = Kws + (size_t)N_BH * S_LEN * D_K;
        prep_k<<<2048, 256, 0, stream>>>(K, Kws);
        prep_v<<<2048, 256, 0, stream>>>(V, Vws);
        sdpa_main<<<512, 256, 0, stream>>>(Q, Kws, Vws, out);
    } else {
        dim3 grid(S_LEN / 64, N_BH);
        sdpa_fused_v1<<<grid, 256, 0, stream>>>(Q, K, V, out);
    }
}

// Round 14
// 167.419 us; speedup vs baseline: 2.0830x; 2.0830x over previous
//
#include <hip/hip_runtime.h>

constexpr int S_LEN = 2048;
constexpr int D_K   = 64;
constexpr int N_BH  = 32;   // B*H
constexpr int KB    = 64;   // k per chunk

typedef __attribute__((ext_vector_type(8))) short short8;
typedef __attribute__((ext_vector_type(4))) short short4v;
typedef __attribute__((ext_vector_type(4))) float f32x4;
typedef unsigned short ushort_t;

__device__ __forceinline__ unsigned short f2bf(float f) {
    unsigned int u = __builtin_bit_cast(unsigned int, f);
    u += 0x7fffu + ((u >> 16) & 1u);          // round-to-nearest-even
    return (unsigned short)(u >> 16);
}
__device__ __forceinline__ float bf2f(unsigned short h) {
    unsigned int u = ((unsigned int)h) << 16;
    return __builtin_bit_cast(float, u);
}

// ============================ prep kernels ============================
__global__ __launch_bounds__(256)
void prep_k(const float* __restrict__ K, ushort_t* __restrict__ Kws) {
    const int idx = blockIdx.x * 256 + threadIdx.x;
    const float4* src = (const float4*)K + (size_t)idx * 2;
    float4 a = src[0], b = src[1];
    float x[8] = {a.x, a.y, a.z, a.w, b.x, b.y, b.z, b.w};
    short8 o;
    #pragma unroll
    for (int j = 0; j < 8; ++j) o[j] = (short)f2bf(x[j] * 0.125f);
    *(short8*)(Kws + (size_t)idx * 8) = o;
}

__global__ __launch_bounds__(256)
void prep_v(const float* __restrict__ V, ushort_t* __restrict__ Vws) {
    const int gid = blockIdx.x * 256 + threadIdx.x;
    const int u   = gid & 511;
    const int bc  = gid >> 9;
    const int c   = bc & 31;
    const int bh  = bc >> 5;
    const int kg  = u >> 6;
    const int d   = u & 63;
    const float* vp = V + ((size_t)bh * S_LEN + c * KB + kg * 8) * D_K + d;
    short8 o;
    #pragma unroll
    for (int i = 0; i < 8; ++i) o[i] = (short)f2bf(vp[(size_t)i * D_K]);
    *(short8*)(Vws + ((size_t)(bh * 32 + c) * D_K + d) * KB + kg * 8) = o;
}

// ============================ main kernel =============================
// R6 structure (best: 173 us) with ONE mechanism changed: QK^T MFMA operands
// are SWAPPED (mfma(K,Q) instead of mfma(Q,K); A and B fragments share the
// same register layout). C-layout (col=lane&15, row=(lane>>4)*4+reg) then
// gives each lane 4 CONSECUTIVE k-columns of ONE q-row per nt:
//   S[q = q0+w*16+lr][k = c*64 + nt*16 + lh*4 + rr]
// -> attn store becomes 4x global_store_dwordx4 (f32-exact, was 16 scalar),
//    Plds staging becomes 4x ds_write_b64 (was 16x b16),
//    row-sum reduce is 2 shuffles (xor 16,32) with a single running scalar.
// Everything else identical to R6: shortest-tiles-first map, dist-2 E/O
// double-buffered staging, hi-only pass 1, swizzled K/V LDS, private Plds.
__global__ __launch_bounds__(256, 4)
void sdpa_main(const float* __restrict__ Q, const ushort_t* __restrict__ Kws,
               const ushort_t* __restrict__ Vws, float* __restrict__ out)
{
    __shared__ __align__(16) ushort_t Kbuf[2][4096];   // 16 KB
    __shared__ __align__(16) ushort_t Vbuf[2][4096];   // 16 KB
    __shared__ __align__(16) ushort_t Plds[4][1024];   //  8 KB (per-wave 16x64)

    const int tid = threadIdx.x;
    const int w   = tid >> 6;      // wave 0..3, owns 16 q rows
    const int l   = tid & 63;
    const int lr  = l & 15;
    const int lh  = l >> 4;

    // tile mapping (R6 original, shortest first): t = {r, 15-r, 16+r, 31-r}
    const int bx  = blockIdx.x;    // 0..1023
    const int g   = bx >> 8;
    const int idx = bx & 255;
    const int bh  = idx >> 3;
    const int r   = idx & 7;
    int t;
    switch (g) {
        case 0:  t = r;      break;
        case 1:  t = 15 - r; break;
        case 2:  t = 16 + r; break;
        default: t = 31 - r; break;
    }
    const int nch = t + 1;
    const int q0  = t * 64;
    const int qg_base = q0 + w * 16 + lh * 4;    // ctx-store rows (PV layout)
    const int qgl     = q0 + w * 16 + lr;        // attn row owned by this lane

    float* ctx_out  = out;                                   // [BH][S][D]
    float* attn_out = out + (size_t)N_BH * S_LEN * D_K;      // [BH][S][S]
    float* arow     = attn_out + ((size_t)bh * S_LEN + qgl) * S_LEN;

    const short8* Kt  = (const short8*)(Kws + (size_t)bh * S_LEN * D_K);   // chunk c at c*512
    const short8* Vt8 = (const short8*)(Vws + (size_t)bh * 32 * 4096);

    // staging: thread writes units tid and tid+256 of each 512-unit chunk
    const int wrow0  = tid >> 3;                  // 0..31
    const int wcol   = (tid & 7) << 4;
    const int wphys0 = wrow0 * 128 + (wcol ^ ((wrow0 & 7) << 4));
    const int wphys1 = wphys0 + 32 * 128;         // rows 32..63, same (row&7)
    const int rsw    = (lr & 7) << 4;             // K/V frag-read swizzle (bytes)

    // ---- Q fragments for my 16 rows, hi/lo bf16 split ----
    short8 qhi[2], qlo[2];
    {
        const float* qrow = Q + ((size_t)bh * S_LEN + q0 + w * 16 + lr) * D_K;
        #pragma unroll
        for (int ds = 0; ds < 2; ++ds) {
            const float4* p4 = (const float4*)(qrow + ds * 32 + lh * 8);
            float4 a = p4[0], bq = p4[1];
            float x[8] = {a.x, a.y, a.z, a.w, bq.x, bq.y, bq.z, bq.w};
            short8 hi, lo;
            #pragma unroll
            for (int j = 0; j < 8; ++j) {
                unsigned short h = f2bf(x[j]);
                hi[j] = (short)h;
                lo[j] = (short)f2bf(x[j] - bf2f(h));
            }
            qhi[ds] = hi; qlo[ds] = lo;
        }
    }

    // ================= PASS 1: row sums (hi-only, swapped QK) =================
    float inv1;
    {
        float sum = 0.f;

        auto p1 = [&](const char* Kb, int c) {
            #pragma unroll
            for (int nt = 0; nt < 4; ++nt) {
                f32x4 acc = {0.f, 0.f, 0.f, 0.f};
                #pragma unroll
                for (int ks = 0; ks < 2; ++ks) {
                    short8 bk = *(const short8*)(Kb + (nt * 16 + lr) * 128 + ((ks * 64 + lh * 16) ^ rsw));
                    acc = __builtin_amdgcn_mfma_f32_16x16x32_bf16(bk, qhi[ks], acc, 0, 0, 0);
                }
                const int kgb = c * KB + nt * 16 + lh * 4;
                #pragma unroll
                for (int rr = 0; rr < 4; ++rr)
                    if (kgb + rr <= qgl) sum += __expf(fminf(acc[rr], 60.f));
            }
        };

        short8 kE0 = Kt[tid], kE1 = Kt[tid + 256];             // chunk 0
        *(short8*)((char*)&Kbuf[0][0] + wphys0) = kE0;
        *(short8*)((char*)&Kbuf[0][0] + wphys1) = kE1;
        short8 kO0 = Kt[512 + tid], kO1 = Kt[512 + tid + 256]; // chunk 1 (always in-bounds)
        __syncthreads();
        for (int c = 0; c < nch; c += 2) {
            if (c + 2 < nch) { kE0 = Kt[(c + 2) * 512 + tid]; kE1 = Kt[(c + 2) * 512 + tid + 256]; }
            p1((const char*)&Kbuf[0][0], c);
            if (c + 1 < nch) {
                *(short8*)((char*)&Kbuf[1][0] + wphys0) = kO0;
                *(short8*)((char*)&Kbuf[1][0] + wphys1) = kO1;
            }
            __syncthreads();
            if (c + 1 < nch) {
                if (c + 3 < nch) { kO0 = Kt[(c + 3) * 512 + tid]; kO1 = Kt[(c + 3) * 512 + tid + 256]; }
                p1((const char*)&Kbuf[1][0], c + 1);
                if (c + 2 < nch) {
                    *(short8*)((char*)&Kbuf[0][0] + wphys0) = kE0;
                    *(short8*)((char*)&Kbuf[0][0] + wphys1) = kE1;
                }
                __syncthreads();
            }
        }
        // row-sum: lanes lr, lr+16, lr+32, lr+48 hold disjoint col-partials
        sum += __shfl_xor(sum, 16);
        sum += __shfl_xor(sum, 32);
        inv1 = 1.f / sum;
    }

    // ================= PASS 2: attn write + PV (hi/lo, swapped QK) =================
    f32x4 ctx[4];
    #pragma unroll
    for (int nt = 0; nt < 4; ++nt) ctx[nt] = (f32x4){0.f, 0.f, 0.f, 0.f};

    {
        auto p2 = [&](const char* Kb, const char* Vb, int c) {
            #pragma unroll
            for (int nt = 0; nt < 4; ++nt) {
                f32x4 acc = {0.f, 0.f, 0.f, 0.f};
                #pragma unroll
                for (int ks = 0; ks < 2; ++ks) {
                    short8 bk = *(const short8*)(Kb + (nt * 16 + lr) * 128 + ((ks * 64 + lh * 16) ^ rsw));
                    acc = __builtin_amdgcn_mfma_f32_16x16x32_bf16(bk, qhi[ks], acc, 0, 0, 0);
                    acc = __builtin_amdgcn_mfma_f32_16x16x32_bf16(bk, qlo[ks], acc, 0, 0, 0);
                }
                const int kgb = c * KB + nt * 16 + lh * 4;   // 4 consecutive cols
                float p0 = (kgb + 0 <= qgl) ? __expf(fminf(acc[0], 60.f)) * inv1 : 0.f;
                float p1v = (kgb + 1 <= qgl) ? __expf(fminf(acc[1], 60.f)) * inv1 : 0.f;
                float p2v = (kgb + 2 <= qgl) ? __expf(fminf(acc[2], 60.f)) * inv1 : 0.f;
                float p3v = (kgb + 3 <= qgl) ? __expf(fminf(acc[3], 60.f)) * inv1 : 0.f;
                *(float4*)(arow + kgb) = (float4){p0, p1v, p2v, p3v};   // f32-exact
                short4v pb;
                pb[0] = (short)f2bf(p0);  pb[1] = (short)f2bf(p1v);
                pb[2] = (short)f2bf(p2v); pb[3] = (short)f2bf(p3v);
                const int colb = nt * 16 + lh * 4;
                *(short4v*)&Plds[w][lr * 64 + (colb ^ ((lr & 7) << 3))] = pb;
            }
            // PV from private Plds (read layout unchanged: row=lr, key lr&7)
            #pragma unroll
            for (int ks = 0; ks < 2; ++ks) {
                short8 pa = *(const short8*)&Plds[w][lr * 64 + ((ks * 32 + lh * 8) ^ ((lr & 7) << 3))];
                #pragma unroll
                for (int nt = 0; nt < 4; ++nt) {
                    short8 vb = *(const short8*)(Vb + (nt * 16 + lr) * 128 + ((ks * 64 + lh * 16) ^ rsw));
                    ctx[nt] = __builtin_amdgcn_mfma_f32_16x16x32_bf16(pa, vb, ctx[nt], 0, 0, 0);
                }
            }
        };

        short8 kE0 = Kt[tid],        kE1 = Kt[tid + 256];
        short8 vE0 = Vt8[tid],       vE1 = Vt8[tid + 256];
        *(short8*)((char*)&Kbuf[0][0] + wphys0) = kE0;
        *(short8*)((char*)&Kbuf[0][0] + wphys1) = kE1;
        *(short8*)((char*)&Vbuf[0][0] + wphys0) = vE0;
        *(short8*)((char*)&Vbuf[0][0] + wphys1) = vE1;
        short8 kO0 = Kt[512 + tid],  kO1 = Kt[512 + tid + 256];
        short8 vO0 = Vt8[512 + tid], vO1 = Vt8[512 + tid + 256];
        __syncthreads();
        for (int c = 0; c < nch; c += 2) {
            if (c + 2 < nch) {
                kE0 = Kt[(c + 2) * 512 + tid];  kE1 = Kt[(c + 2) * 512 + tid + 256];
                vE0 = Vt8[(c + 2) * 512 + tid]; vE1 = Vt8[(c + 2) * 512 + tid + 256];
            }
            p2((const char*)&Kbuf[0][0], (const char*)&Vbuf[0][0], c);
            if (c + 1 < nch) {
                *(short8*)((char*)&Kbuf[1][0] + wphys0) = kO0;
                *(short8*)((char*)&Kbuf[1][0] + wphys1) = kO1;
                *(short8*)((char*)&Vbuf[1][0] + wphys0) = vO0;
                *(short8*)((char*)&Vbuf[1][0] + wphys1) = vO1;
            }
            __syncthreads();
            if (c + 1 < nch) {
                if (c + 3 < nch) {
                    kO0 = Kt[(c + 3) * 512 + tid];  kO1 = Kt[(c + 3) * 512 + tid + 256];
                    vO0 = Vt8[(c + 3) * 512 + tid]; vO1 = Vt8[(c + 3) * 512 + tid + 256];
                }
                p2((const char*)&Kbuf[1][0], (const char*)&Vbuf[1][0], c + 1);
                if (c + 2 < nch) {
                    *(short8*)((char*)&Kbuf[0][0] + wphys0) = kE0;
                    *(short8*)((char*)&Kbuf[0][0] + wphys1) = kE1;
                    *(short8*)((char*)&Vbuf[0][0] + wphys0) = vE0;
                    *(short8*)((char*)&Vbuf[0][0] + wphys1) = vE1;
                }
                __syncthreads();
            }
        }
    }

    // context stores: PV C-layout rows (qg_base+rr), cols nt*16+lr — unchanged
    #pragma unroll
    for (int nt = 0; nt < 4; ++nt)
        #pragma unroll
        for (int rr = 0; rr < 4; ++rr)
            ctx_out[((size_t)bh * S_LEN + qg_base + rr) * D_K + nt * 16 + lr] = ctx[nt][rr];

    // zero-fill fully-masked tail columns (64 rows, 4 threads/row)
    const int k0 = nch * KB;
    if (k0 < S_LEN) {
        const float4 z = {0.f, 0.f, 0.f, 0.f};
        float* rowp = attn_out + ((size_t)bh * S_LEN + q0 + (tid >> 2)) * S_LEN;
        for (int k = k0 + (tid & 3) * 4; k < S_LEN; k += 16)
            *(float4*)(rowp + k) = z;
    }
}

// ===================== fallback (round-1 kernel, no ws) =====================
constexpr int LDP = 72;

__global__ __launch_bounds__(256)
void sdpa_fused_v1(const float* __restrict__ Q, const float* __restrict__ K,
                   const float* __restrict__ V, float* __restrict__ out)
{
    __shared__ __align__(16) unsigned short Klds[KB * LDP];
    __shared__ __align__(16) unsigned short Vtlds[D_K * LDP];
    __shared__ __align__(16) unsigned short Pl[4][16 * LDP];

    const int tid = threadIdx.x;
    const int w   = tid >> 6;
    const int l   = tid & 63;
    const int lr  = l & 15;
    const int lh  = l >> 4;

    const int bh   = blockIdx.y;
    const int qblk = (int)gridDim.x - 1 - (int)blockIdx.x;
    const int q0   = qblk * 64;
    const int qw   = q0 + w * 16;
    const int nchunks = qblk + 1;

    const size_t in_base = (size_t)bh * S_LEN * D_K;
    float* ctx_out  = out;
    float* attn_out = out + (size_t)N_BH * S_LEN * D_K;

    short8 qhi[2], qlo[2];
    {
        const float* qrow = Q + in_base + (size_t)(qw + lr) * D_K;
        #pragma unroll
        for (int ds = 0; ds < 2; ++ds) {
            const float4* p4 = (const float4*)(qrow + ds * 32 + lh * 8);
            float4 a = p4[0], b = p4[1];
            float x[8] = {a.x, a.y, a.z, a.w, b.x, b.y, b.z, b.w};
            short8 hi, lo;
            #pragma unroll
            for (int j = 0; j < 8; ++j) {
                unsigned short h = f2bf(x[j]);
                hi[j] = (short)h;
                lo[j] = (short)f2bf(x[j] - bf2f(h));
            }
            qhi[ds] = hi; qlo[ds] = lo;
        }
    }

    const int srow = tid >> 2;
    const int scol = (tid & 3) * 16;
    const float* kstage = K + in_base + (size_t)srow * D_K + scol;
    const float* vstage = V + in_base + (size_t)srow * D_K + scol;

    float inv_[4];
    {
        float sum[4] = {0.f, 0.f, 0.f, 0.f};
        for (int c = 0; c < nchunks; ++c) {
            {
                const float4* kp = (const float4*)(kstage + (size_t)c * KB * D_K);
                float4 a0 = kp[0], a1 = kp[1], a2 = kp[2], a3 = kp[3];
                float x[16] = {a0.x,a0.y,a0.z,a0.w, a1.x,a1.y,a1.z,a1.w,
                               a2.x,a2.y,a2.z,a2.w, a3.x,a3.y,a3.z,a3.w};
                short8 w0, w1;
                #pragma unroll
                for (int j = 0; j < 8; ++j) {
                    w0[j] = (short)f2bf(x[j]     * 0.125f);
                    w1[j] = (short)f2bf(x[j + 8] * 0.125f);
                }
                *(short8*)&Klds[srow * LDP + scol]     = w0;
                *(short8*)&Klds[srow * LDP + scol + 8] = w1;
            }
            __syncthreads();
            #pragma unroll
            for (int nt = 0; nt < 4; ++nt) {
                f32x4 acc = {0.f, 0.f, 0.f, 0.f};
                #pragma unroll
                for (int ks = 0; ks < 2; ++ks) {
                    short8 bk = *(const short8*)&Klds[(nt*16 + lr) * LDP + ks*32 + lh*8];
                    acc = __builtin_amdgcn_mfma_f32_16x16x32_bf16(qhi[ks], bk, acc, 0, 0, 0);
                    acc = __builtin_amdgcn_mfma_f32_16x16x32_bf16(qlo[ks], bk, acc, 0, 0, 0);
                }
                const int kg = c * KB + nt * 16 + lr;
                #pragma unroll
                for (int rr = 0; rr < 4; ++rr) {
                    if (kg <= qw + lh * 4 + rr)
                        sum[rr] += __expf(fminf(acc[rr], 60.f));
                }
            }
            __syncthreads();
        }
        #pragma unroll
        for (int rr = 0; rr < 4; ++rr) {
            float t = sum[rr];
            t += __shfl_xor(t, 1);
            t += __shfl_xor(t, 2);
            t += __shfl_xor(t, 4);
            t += __shfl_xor(t, 8);
            inv_[rr] = 1.f / t;
        }
    }

    f32x4 ctx[4];
    #pragma unroll
    for (int nt = 0; nt < 4; ++nt) ctx[nt] = (f32x4){0.f, 0.f, 0.f, 0.f};

    for (int c = 0; c < nchunks; ++c) {
        {
            const float4* kp = (const float4*)(kstage + (size_t)c * KB * D_K);
            float4 a0 = kp[0], a1 = kp[1], a2 = kp[2], a3 = kp[3];
            float x[16] = {a0.x,a0.y,a0.z,a0.w, a1.x,a1.y,a1.z,a1.w,
                           a2.x,a2.y,a2.z,a2.w, a3.x,a3.y,a3.z,a3.w};
            short8 w0, w1;
            #pragma unroll
            for (int j = 0; j < 8; ++j) {
                w0[j] = (short)f2bf(x[j]     * 0.125f);
                w1[j] = (short)f2bf(x[j + 8] * 0.125f);
            }
            *(short8*)&Klds[srow * LDP + scol]     = w0;
            *(short8*)&Klds[srow * LDP + scol + 8] = w1;

            const float4* vp = (const float4*)(vstage + (size_t)c * KB * D_K);
            float4 b0 = vp[0], b1 = vp[1], b2 = vp[2], b3 = vp[3];
            float y[16] = {b0.x,b0.y,b0.z,b0.w, b1.x,b1.y,b1.z,b1.w,
                           b2.x,b2.y,b2.z,b2.w, b3.x,b3.y,b3.z,b3.w};
            #pragma unroll
            for (int j = 0; j < 16; ++j)
                Vtlds[(scol + j) * LDP + srow] = f2bf(y[j]);
        }
        __syncthreads();

        #pragma unroll
        for (int nt = 0; nt < 4; ++nt) {
            f32x4 acc = {0.f, 0.f, 0.f, 0.f};
            #pragma unroll
            for (int ks = 0; ks < 2; ++ks) {
                short8 bk = *(const short8*)&Klds[(nt*16 + lr) * LDP + ks*32 + lh*8];
                acc = __builtin_amdgcn_mfma_f32_16x16x32_bf16(qhi[ks], bk, acc, 0, 0, 0);
                acc = __builtin_amdgcn_mfma_f32_16x16x32_bf16(qlo[ks], bk, acc, 0, 0, 0);
            }
            const int kg = c * KB + nt * 16 + lr;
            #pragma unroll
            for (int rr = 0; rr < 4; ++rr) {
                const int qg = qw + lh * 4 + rr;
                float p = (kg <= qg) ? __expf(fminf(acc[rr], 60.f)) * inv_[rr] : 0.f;
                attn_out[((size_t)bh * S_LEN + qg) * S_LEN + kg] = p;
                Pl[w][(lh * 4 + rr) * LDP + nt * 16 + lr] = f2bf(p);
            }
        }
        __syncthreads();

        #pragma unroll
        for (int ks = 0; ks < 2; ++ks) {
            short8 pa = *(const short8*)&Pl[w][lr * LDP + ks*32 + lh*8];
            #pragma unroll
            for (int nt = 0; nt < 4; ++nt) {
                short8 vb = *(const short8*)&Vtlds[(nt*16 + lr) * LDP + ks*32 + lh*8];
                ctx[nt] = __builtin_amdgcn_mfma_f32_16x16x32_bf16(pa, vb, ctx[nt], 0, 0, 0);
            }
        }
        __syncthreads();
    }

    #pragma unroll
    for (int nt = 0; nt < 4; ++nt)
        #pragma unroll
        for (int rr = 0; rr < 4; ++rr)
            ctx_out[((size_t)bh * S_LEN + qw + lh * 4 + rr) * D_K + nt * 16 + lr] = ctx[nt][rr];

    const int k0 = nchunks * KB;
    if (k0 < S_LEN) {
        const float4 z = {0.f, 0.f, 0.f, 0.f};
        for (int rr = 0; rr < 64; ++rr) {
            float* rowp = attn_out + ((size_t)bh * S_LEN + q0 + rr) * S_LEN;
            for (int k = k0 + tid * 4; k < S_LEN; k += 256 * 4)
                *(float4*)(rowp + k) = z;
        }
    }
}

extern "C" void kernel_launch(void* const* d_in, const int* in_sizes, int n_in,
                              void* d_out, int out_size, void* d_ws, size_t ws_size,
                              hipStream_t stream)
{
    const float* Q = (const float*)d_in[0];
    const float* K = (const float*)d_in[1];
    const float* V = (const float*)d_in[2];
    float* out = (float*)d_out;

    const size_t ws_needed = (size_t)2 * N_BH * S_LEN * D_K * sizeof(ushort_t);  // 16.8 MB
    if (ws_size >= ws_needed) {
        ushort_t* Kws = (ushort_t*)d_ws;
        ushort_t* Vws = Kws + (size_t)N_BH * S_LEN * D_K;
        prep_k<<<2048, 256, 0, stream>>>(K, Kws);
        prep_v<<<2048, 256, 0, stream>>>(V, Vws);
        sdpa_main<<<1024, 256, 0, stream>>>(Q, Kws, Vws, out);
    } else {
        dim3 grid(S_LEN / 64, N_BH);
        sdpa_fused_v1<<<grid, 256, 0, stream>>>(Q, K, V, out);
    }
}

// Round 15
// 166.096 us; speedup vs baseline: 2.0996x; 1.0080x over previous
//
#include <hip/hip_runtime.h>

constexpr int S_LEN = 2048;
constexpr int D_K   = 64;
constexpr int N_BH  = 32;   // B*H
constexpr int KB    = 64;   // k per chunk

typedef __attribute__((ext_vector_type(8))) short short8;
typedef __attribute__((ext_vector_type(4))) short short4v;
typedef __attribute__((ext_vector_type(4))) float f32x4;
typedef unsigned short ushort_t;

__device__ __forceinline__ unsigned short f2bf(float f) {
    unsigned int u = __builtin_bit_cast(unsigned int, f);
    u += 0x7fffu + ((u >> 16) & 1u);          // round-to-nearest-even
    return (unsigned short)(u >> 16);
}
__device__ __forceinline__ float bf2f(unsigned short h) {
    unsigned int u = ((unsigned int)h) << 16;
    return __builtin_bit_cast(float, u);
}

// ============================ prep kernel (K + V in one launch) ============
// blocks 0..2047   : K -> bf16 * 0.125, same [bh][s][d] layout
// blocks 2048..4095: V -> bf16 transposed per 64-chunk: Vws[bh][c][d][k]
__global__ __launch_bounds__(256)
void prep_kv(const float* __restrict__ K, const float* __restrict__ V,
             ushort_t* __restrict__ Kws, ushort_t* __restrict__ Vws)
{
    const int bxl = blockIdx.x;
    if (bxl < 2048) {
        const int idx = bxl * 256 + threadIdx.x;
        const float4* src = (const float4*)K + (size_t)idx * 2;
        float4 a = src[0], b = src[1];
        float x[8] = {a.x, a.y, a.z, a.w, b.x, b.y, b.z, b.w};
        short8 o;
        #pragma unroll
        for (int j = 0; j < 8; ++j) o[j] = (short)f2bf(x[j] * 0.125f);
        *(short8*)(Kws + (size_t)idx * 8) = o;
    } else {
        const int gid = (bxl - 2048) * 256 + threadIdx.x;
        const int u   = gid & 511;
        const int bc  = gid >> 9;
        const int c   = bc & 31;
        const int bh  = bc >> 5;
        const int kg  = u >> 6;
        const int d   = u & 63;
        const float* vp = V + ((size_t)bh * S_LEN + c * KB + kg * 8) * D_K + d;
        short8 o;
        #pragma unroll
        for (int i = 0; i < 8; ++i) o[i] = (short)f2bf(vp[(size_t)i * D_K]);
        *(short8*)(Vws + ((size_t)(bh * 32 + c) * D_K + d) * KB + kg * 8) = o;
    }
}

// ============================ main kernel =============================
// R14 (best: 167.4 us): swapped-QK epilogue (4x dwordx4 attn stores, b64
// P-staging, 2-shuffle row-sum), shortest-first tile map, dist-2 E/O
// double-buffered staging, hi-only pass 1, swizzled K/V LDS, private Plds.
// R15 delta: full-line zero-fill (8 lanes x float4 = 128 B/row/instr).
__global__ __launch_bounds__(256, 4)
void sdpa_main(const float* __restrict__ Q, const ushort_t* __restrict__ Kws,
               const ushort_t* __restrict__ Vws, float* __restrict__ out)
{
    __shared__ __align__(16) ushort_t Kbuf[2][4096];   // 16 KB
    __shared__ __align__(16) ushort_t Vbuf[2][4096];   // 16 KB
    __shared__ __align__(16) ushort_t Plds[4][1024];   //  8 KB (per-wave 16x64)

    const int tid = threadIdx.x;
    const int w   = tid >> 6;      // wave 0..3, owns 16 q rows
    const int l   = tid & 63;
    const int lr  = l & 15;
    const int lh  = l >> 4;

    // tile mapping (shortest first): t = {r, 15-r, 16+r, 31-r}
    const int bx  = blockIdx.x;    // 0..1023
    const int g   = bx >> 8;
    const int idx = bx & 255;
    const int bh  = idx >> 3;
    const int r   = idx & 7;
    int t;
    switch (g) {
        case 0:  t = r;      break;
        case 1:  t = 15 - r; break;
        case 2:  t = 16 + r; break;
        default: t = 31 - r; break;
    }
    const int nch = t + 1;
    const int q0  = t * 64;
    const int qg_base = q0 + w * 16 + lh * 4;    // ctx-store rows (PV layout)
    const int qgl     = q0 + w * 16 + lr;        // attn row owned by this lane

    float* ctx_out  = out;                                   // [BH][S][D]
    float* attn_out = out + (size_t)N_BH * S_LEN * D_K;      // [BH][S][S]
    float* arow     = attn_out + ((size_t)bh * S_LEN + qgl) * S_LEN;

    const short8* Kt  = (const short8*)(Kws + (size_t)bh * S_LEN * D_K);   // chunk c at c*512
    const short8* Vt8 = (const short8*)(Vws + (size_t)bh * 32 * 4096);

    // staging: thread writes units tid and tid+256 of each 512-unit chunk
    const int wrow0  = tid >> 3;                  // 0..31
    const int wcol   = (tid & 7) << 4;
    const int wphys0 = wrow0 * 128 + (wcol ^ ((wrow0 & 7) << 4));
    const int wphys1 = wphys0 + 32 * 128;         // rows 32..63, same (row&7)
    const int rsw    = (lr & 7) << 4;             // K/V frag-read swizzle (bytes)

    // ---- Q fragments for my 16 rows, hi/lo bf16 split ----
    short8 qhi[2], qlo[2];
    {
        const float* qrow = Q + ((size_t)bh * S_LEN + q0 + w * 16 + lr) * D_K;
        #pragma unroll
        for (int ds = 0; ds < 2; ++ds) {
            const float4* p4 = (const float4*)(qrow + ds * 32 + lh * 8);
            float4 a = p4[0], bq = p4[1];
            float x[8] = {a.x, a.y, a.z, a.w, bq.x, bq.y, bq.z, bq.w};
            short8 hi, lo;
            #pragma unroll
            for (int j = 0; j < 8; ++j) {
                unsigned short h = f2bf(x[j]);
                hi[j] = (short)h;
                lo[j] = (short)f2bf(x[j] - bf2f(h));
            }
            qhi[ds] = hi; qlo[ds] = lo;
        }
    }

    // ================= PASS 1: row sums (hi-only, swapped QK) =================
    float inv1;
    {
        float sum = 0.f;

        auto p1 = [&](const char* Kb, int c) {
            #pragma unroll
            for (int nt = 0; nt < 4; ++nt) {
                f32x4 acc = {0.f, 0.f, 0.f, 0.f};
                #pragma unroll
                for (int ks = 0; ks < 2; ++ks) {
                    short8 bk = *(const short8*)(Kb + (nt * 16 + lr) * 128 + ((ks * 64 + lh * 16) ^ rsw));
                    acc = __builtin_amdgcn_mfma_f32_16x16x32_bf16(bk, qhi[ks], acc, 0, 0, 0);
                }
                const int kgb = c * KB + nt * 16 + lh * 4;
                #pragma unroll
                for (int rr = 0; rr < 4; ++rr)
                    if (kgb + rr <= qgl) sum += __expf(fminf(acc[rr], 60.f));
            }
        };

        short8 kE0 = Kt[tid], kE1 = Kt[tid + 256];             // chunk 0
        *(short8*)((char*)&Kbuf[0][0] + wphys0) = kE0;
        *(short8*)((char*)&Kbuf[0][0] + wphys1) = kE1;
        short8 kO0 = Kt[512 + tid], kO1 = Kt[512 + tid + 256]; // chunk 1 (always in-bounds)
        __syncthreads();
        for (int c = 0; c < nch; c += 2) {
            if (c + 2 < nch) { kE0 = Kt[(c + 2) * 512 + tid]; kE1 = Kt[(c + 2) * 512 + tid + 256]; }
            p1((const char*)&Kbuf[0][0], c);
            if (c + 1 < nch) {
                *(short8*)((char*)&Kbuf[1][0] + wphys0) = kO0;
                *(short8*)((char*)&Kbuf[1][0] + wphys1) = kO1;
            }
            __syncthreads();
            if (c + 1 < nch) {
                if (c + 3 < nch) { kO0 = Kt[(c + 3) * 512 + tid]; kO1 = Kt[(c + 3) * 512 + tid + 256]; }
                p1((const char*)&Kbuf[1][0], c + 1);
                if (c + 2 < nch) {
                    *(short8*)((char*)&Kbuf[0][0] + wphys0) = kE0;
                    *(short8*)((char*)&Kbuf[0][0] + wphys1) = kE1;
                }
                __syncthreads();
            }
        }
        // row-sum: lanes lr, lr+16, lr+32, lr+48 hold disjoint col-partials
        sum += __shfl_xor(sum, 16);
        sum += __shfl_xor(sum, 32);
        inv1 = 1.f / sum;
    }

    // ================= PASS 2: attn write + PV (hi/lo, swapped QK) =================
    f32x4 ctx[4];
    #pragma unroll
    for (int nt = 0; nt < 4; ++nt) ctx[nt] = (f32x4){0.f, 0.f, 0.f, 0.f};

    {
        auto p2 = [&](const char* Kb, const char* Vb, int c) {
            #pragma unroll
            for (int nt = 0; nt < 4; ++nt) {
                f32x4 acc = {0.f, 0.f, 0.f, 0.f};
                #pragma unroll
                for (int ks = 0; ks < 2; ++ks) {
                    short8 bk = *(const short8*)(Kb + (nt * 16 + lr) * 128 + ((ks * 64 + lh * 16) ^ rsw));
                    acc = __builtin_amdgcn_mfma_f32_16x16x32_bf16(bk, qhi[ks], acc, 0, 0, 0);
                    acc = __builtin_amdgcn_mfma_f32_16x16x32_bf16(bk, qlo[ks], acc, 0, 0, 0);
                }
                const int kgb = c * KB + nt * 16 + lh * 4;   // 4 consecutive cols
                float p0 = (kgb + 0 <= qgl) ? __expf(fminf(acc[0], 60.f)) * inv1 : 0.f;
                float p1v = (kgb + 1 <= qgl) ? __expf(fminf(acc[1], 60.f)) * inv1 : 0.f;
                float p2v = (kgb + 2 <= qgl) ? __expf(fminf(acc[2], 60.f)) * inv1 : 0.f;
                float p3v = (kgb + 3 <= qgl) ? __expf(fminf(acc[3], 60.f)) * inv1 : 0.f;
                *(float4*)(arow + kgb) = (float4){p0, p1v, p2v, p3v};   // f32-exact
                short4v pb;
                pb[0] = (short)f2bf(p0);  pb[1] = (short)f2bf(p1v);
                pb[2] = (short)f2bf(p2v); pb[3] = (short)f2bf(p3v);
                const int colb = nt * 16 + lh * 4;
                *(short4v*)&Plds[w][lr * 64 + (colb ^ ((lr & 7) << 3))] = pb;
            }
            // PV from private Plds (read layout unchanged: row=lr, key lr&7)
            #pragma unroll
            for (int ks = 0; ks < 2; ++ks) {
                short8 pa = *(const short8*)&Plds[w][lr * 64 + ((ks * 32 + lh * 8) ^ ((lr & 7) << 3))];
                #pragma unroll
                for (int nt = 0; nt < 4; ++nt) {
                    short8 vb = *(const short8*)(Vb + (nt * 16 + lr) * 128 + ((ks * 64 + lh * 16) ^ rsw));
                    ctx[nt] = __builtin_amdgcn_mfma_f32_16x16x32_bf16(pa, vb, ctx[nt], 0, 0, 0);
                }
            }
        };

        short8 kE0 = Kt[tid],        kE1 = Kt[tid + 256];
        short8 vE0 = Vt8[tid],       vE1 = Vt8[tid + 256];
        *(short8*)((char*)&Kbuf[0][0] + wphys0) = kE0;
        *(short8*)((char*)&Kbuf[0][0] + wphys1) = kE1;
        *(short8*)((char*)&Vbuf[0][0] + wphys0) = vE0;
        *(short8*)((char*)&Vbuf[0][0] + wphys1) = vE1;
        short8 kO0 = Kt[512 + tid],  kO1 = Kt[512 + tid + 256];
        short8 vO0 = Vt8[512 + tid], vO1 = Vt8[512 + tid + 256];
        __syncthreads();
        for (int c = 0; c < nch; c += 2) {
            if (c + 2 < nch) {
                kE0 = Kt[(c + 2) * 512 + tid];  kE1 = Kt[(c + 2) * 512 + tid + 256];
                vE0 = Vt8[(c + 2) * 512 + tid]; vE1 = Vt8[(c + 2) * 512 + tid + 256];
            }
            p2((const char*)&Kbuf[0][0], (const char*)&Vbuf[0][0], c);
            if (c + 1 < nch) {
                *(short8*)((char*)&Kbuf[1][0] + wphys0) = kO0;
                *(short8*)((char*)&Kbuf[1][0] + wphys1) = kO1;
                *(short8*)((char*)&Vbuf[1][0] + wphys0) = vO0;
                *(short8*)((char*)&Vbuf[1][0] + wphys1) = vO1;
            }
            __syncthreads();
            if (c + 1 < nch) {
                if (c + 3 < nch) {
                    kO0 = Kt[(c + 3) * 512 + tid];  kO1 = Kt[(c + 3) * 512 + tid + 256];
                    vO0 = Vt8[(c + 3) * 512 + tid]; vO1 = Vt8[(c + 3) * 512 + tid + 256];
                }
                p2((const char*)&Kbuf[1][0], (const char*)&Vbuf[1][0], c + 1);
                if (c + 2 < nch) {
                    *(short8*)((char*)&Kbuf[0][0] + wphys0) = kE0;
                    *(short8*)((char*)&Kbuf[0][0] + wphys1) = kE1;
                    *(short8*)((char*)&Vbuf[0][0] + wphys0) = vE0;
                    *(short8*)((char*)&Vbuf[0][0] + wphys1) = vE1;
                }
                __syncthreads();
            }
        }
    }

    // context stores: PV C-layout rows (qg_base+rr), cols nt*16+lr
    #pragma unroll
    for (int nt = 0; nt < 4; ++nt)
        #pragma unroll
        for (int rr = 0; rr < 4; ++rr)
            ctx_out[((size_t)bh * S_LEN + qg_base + rr) * D_K + nt * 16 + lr] = ctx[nt][rr];

    // zero-fill fully-masked tail columns: 8 lanes x float4 = 128 B (full
    // L2 line) per row per instruction; 32 rows/wave-pass, 2 passes.
    const int k0 = nch * KB;
    if (k0 < S_LEN) {
        const float4 z = {0.f, 0.f, 0.f, 0.f};
        #pragma unroll
        for (int rbase = 0; rbase < 64; rbase += 32) {
            float* rowp = attn_out + ((size_t)bh * S_LEN + q0 + rbase + (tid >> 3)) * S_LEN;
            for (int k = k0 + (tid & 7) * 4; k < S_LEN; k += 32)
                *(float4*)(rowp + k) = z;
        }
    }
}

// ===================== fallback (round-1 kernel, no ws) =====================
constexpr int LDP = 72;

__global__ __launch_bounds__(256)
void sdpa_fused_v1(const float* __restrict__ Q, const float* __restrict__ K,
                   const float* __restrict__ V, float* __restrict__ out)
{
    __shared__ __align__(16) unsigned short Klds[KB * LDP];
    __shared__ __align__(16) unsigned short Vtlds[D_K * LDP];
    __shared__ __align__(16) unsigned short Pl[4][16 * LDP];

    const int tid = threadIdx.x;
    const int w   = tid >> 6;
    const int l   = tid & 63;
    const int lr  = l & 15;
    const int lh  = l >> 4;

    const int bh   = blockIdx.y;
    const int qblk = (int)gridDim.x - 1 - (int)blockIdx.x;
    const int q0   = qblk * 64;
    const int qw   = q0 + w * 16;
    const int nchunks = qblk + 1;

    const size_t in_base = (size_t)bh * S_LEN * D_K;
    float* ctx_out  = out;
    float* attn_out = out + (size_t)N_BH * S_LEN * D_K;

    short8 qhi[2], qlo[2];
    {
        const float* qrow = Q + in_base + (size_t)(qw + lr) * D_K;
        #pragma unroll
        for (int ds = 0; ds < 2; ++ds) {
            const float4* p4 = (const float4*)(qrow + ds * 32 + lh * 8);
            float4 a = p4[0], b = p4[1];
            float x[8] = {a.x, a.y, a.z, a.w, b.x, b.y, b.z, b.w};
            short8 hi, lo;
            #pragma unroll
            for (int j = 0; j < 8; ++j) {
                unsigned short h = f2bf(x[j]);
                hi[j] = (short)h;
                lo[j] = (short)f2bf(x[j] - bf2f(h));
            }
            qhi[ds] = hi; qlo[ds] = lo;
        }
    }

    const int srow = tid >> 2;
    const int scol = (tid & 3) * 16;
    const float* kstage = K + in_base + (size_t)srow * D_K + scol;
    const float* vstage = V + in_base + (size_t)srow * D_K + scol;

    float inv_[4];
    {
        float sum[4] = {0.f, 0.f, 0.f, 0.f};
        for (int c = 0; c < nchunks; ++c) {
            {
                const float4* kp = (const float4*)(kstage + (size_t)c * KB * D_K);
                float4 a0 = kp[0], a1 = kp[1], a2 = kp[2], a3 = kp[3];
                float x[16] = {a0.x,a0.y,a0.z,a0.w, a1.x,a1.y,a1.z,a1.w,
                               a2.x,a2.y,a2.z,a2.w, a3.x,a3.y,a3.z,a3.w};
                short8 w0, w1;
                #pragma unroll
                for (int j = 0; j < 8; ++j) {
                    w0[j] = (short)f2bf(x[j]     * 0.125f);
                    w1[j] = (short)f2bf(x[j + 8] * 0.125f);
                }
                *(short8*)&Klds[srow * LDP + scol]     = w0;
                *(short8*)&Klds[srow * LDP + scol + 8] = w1;
            }
            __syncthreads();
            #pragma unroll
            for (int nt = 0; nt < 4; ++nt) {
                f32x4 acc = {0.f, 0.f, 0.f, 0.f};
                #pragma unroll
                for (int ks = 0; ks < 2; ++ks) {
                    short8 bk = *(const short8*)&Klds[(nt*16 + lr) * LDP + ks*32 + lh*8];
                    acc = __builtin_amdgcn_mfma_f32_16x16x32_bf16(qhi[ks], bk, acc, 0, 0, 0);
                    acc = __builtin_amdgcn_mfma_f32_16x16x32_bf16(qlo[ks], bk, acc, 0, 0, 0);
                }
                const int kg = c * KB + nt * 16 + lr;
                #pragma unroll
                for (int rr = 0; rr < 4; ++rr) {
                    if (kg <= qw + lh * 4 + rr)
                        sum[rr] += __expf(fminf(acc[rr], 60.f));
                }
            }
            __syncthreads();
        }
        #pragma unroll
        for (int rr = 0; rr < 4; ++rr) {
            float t = sum[rr];
            t += __shfl_xor(t, 1);
            t += __shfl_xor(t, 2);
            t += __shfl_xor(t, 4);
            t += __shfl_xor(t, 8);
            inv_[rr] = 1.f / t;
        }
    }

    f32x4 ctx[4];
    #pragma unroll
    for (int nt = 0; nt < 4; ++nt) ctx[nt] = (f32x4){0.f, 0.f, 0.f, 0.f};

    for (int c = 0; c < nchunks; ++c) {
        {
            const float4* kp = (const float4*)(kstage + (size_t)c * KB * D_K);
            float4 a0 = kp[0], a1 = kp[1], a2 = kp[2], a3 = kp[3];
            float x[16] = {a0.x,a0.y,a0.z,a0.w, a1.x,a1.y,a1.z,a1.w,
                           a2.x,a2.y,a2.z,a2.w, a3.x,a3.y,a3.z,a3.w};
            short8 w0, w1;
            #pragma unroll
            for (int j = 0; j < 8; ++j) {
                w0[j] = (short)f2bf(x[j]     * 0.125f);
                w1[j] = (short)f2bf(x[j + 8] * 0.125f);
            }
            *(short8*)&Klds[srow * LDP + scol]     = w0;
            *(short8*)&Klds[srow * LDP + scol + 8] = w1;

            const float4* vp = (const float4*)(vstage + (size_t)c * KB * D_K);
            float4 b0 = vp[0], b1 = vp[1], b2 = vp[2], b3 = vp[3];
            float y[16] = {b0.x,b0.y,b0.z,b0.w, b1.x,b1.y,b1.z,b1.w,
                           b2.x,b2.y,b2.z,b2.w, b3.x,b3.y,b3.z,b3.w};
            #pragma unroll
            for (int j = 0; j < 16; ++j)
                Vtlds[(scol + j) * LDP + srow] = f2bf(y[j]);
        }
        __syncthreads();

        #pragma unroll
        for (int nt = 0; nt < 4; ++nt) {
            f32x4 acc = {0.f, 0.f, 0.f, 0.f};
            #pragma unroll
            for (int ks = 0; ks < 2; ++ks) {
                short8 bk = *(const short8*)&Klds[(nt*16 + lr) * LDP + ks*32 + lh*8];
                acc = __builtin_amdgcn_mfma_f32_16x16x32_bf16(qhi[ks], bk, acc, 0, 0, 0);
                acc = __builtin_amdgcn_mfma_f32_16x16x32_bf16(qlo[ks], bk, acc, 0, 0, 0);
            }
            const int kg = c * KB + nt * 16 + lr;
            #pragma unroll
            for (int rr = 0; rr < 4; ++rr) {
                const int qg = qw + lh * 4 + rr;
                float p = (kg <= qg) ? __expf(fminf(acc[rr], 60.f)) * inv_[rr] : 0.f;
                attn_out[((size_t)bh * S_LEN + qg) * S_LEN + kg] = p;
                Pl[w][(lh * 4 + rr) * LDP + nt * 16 + lr] = f2bf(p);
            }
        }
        __syncthreads();

        #pragma unroll
        for (int ks = 0; ks < 2; ++ks) {
            short8 pa = *(const short8*)&Pl[w][lr * LDP + ks*32 + lh*8];
            #pragma unroll
            for (int nt = 0; nt < 4; ++nt) {
                short8 vb = *(const short8*)&Vtlds[(nt*16 + lr) * LDP + ks*32 + lh*8];
                ctx[nt] = __builtin_amdgcn_mfma_f32_16x16x32_bf16(pa, vb, ctx[nt], 0, 0, 0);
            }
        }
        __syncthreads();
    }

    #pragma unroll
    for (int nt = 0; nt < 4; ++nt)
        #pragma unroll
        for (int rr = 0; rr < 4; ++rr)
            ctx_out[((size_t)bh * S_LEN + qw + lh * 4 + rr) * D_K + nt * 16 + lr] = ctx[nt][rr];

    const int k0 = nchunks * KB;
    if (k0 < S_LEN) {
        const float4 z = {0.f, 0.f, 0.f, 0.f};
        for (int rr = 0; rr < 64; ++rr) {
            float* rowp = attn_out + ((size_t)bh * S_LEN + q0 + rr) * S_LEN;
            for (int k = k0 + tid * 4; k < S_LEN; k += 256 * 4)
                *(float4*)(rowp + k) = z;
        }
    }
}

extern "C" void kernel_launch(void* const* d_in, const int* in_sizes, int n_in,
                              void* d_out, int out_size, void* d_ws, size_t ws_size,
                              hipStream_t stream)
{
    const float* Q = (const float*)d_in[0];
    const float* K = (const float*)d_in[1];
    const float* V = (const float*)d_in[2];
    float* out = (float*)d_out;

    const size_t ws_needed = (size_t)2 * N_BH * S_LEN * D_K * sizeof(ushort_t);  // 16.8 MB
    if (ws_size >= ws_needed) {
        ushort_t* Kws = (ushort_t*)d_ws;
        ushort_t* Vws = Kws + (size_t)N_BH * S_LEN * D_K;
        prep_kv<<<4096, 256, 0, stream>>>(K, V, Kws, Vws);
        sdpa_main<<<1024, 256, 0, stream>>>(Q, Kws, Vws, out);
    } else {
        dim3 grid(S_LEN / 64, N_BH);
        sdpa_fused_v1<<<grid, 256, 0, stream>>>(Q, K, V, out);
    }
}